// Round 1
// baseline (13999.538 us; speedup 1.0000x reference)
//
#include <hip/hip_runtime.h>
#include <hip/hip_bf16.h>
#include <math.h>

// Problem constants
#define VV 32000
#define EE 512
#define DD 1024
#define TE 1024
#define BB 32
#define SS 64
#define TT 48

// ---------------------------------------------------------------------------
// init: hA=h0, cA=c0, av(prev_context)=0
// ---------------------------------------------------------------------------
__global__ void init_k(const float* __restrict__ h0, const float* __restrict__ c0,
                       float* __restrict__ hA, float* __restrict__ cA,
                       float* __restrict__ av) {
  int i = blockIdx.x * 256 + threadIdx.x;
  if (i < BB * DD) { hA[i] = h0[i]; cA[i] = c0[i]; av[i] = 0.f; }
}

// ---------------------------------------------------------------------------
// Generic fp32 GEMM: C[M,N] = A[M,K] @ B[N,K]^T, all row-major.
// M,N multiples of 64; K multiple of 16. 64x64 C-tile, 4x4 per thread.
// ---------------------------------------------------------------------------
__global__ __launch_bounds__(256) void gemm_nt(
    const float* __restrict__ A, const float* __restrict__ Bm,
    float* __restrict__ C, int M, int N, int K) {
  __shared__ float As[64][17];
  __shared__ float Bs[64][17];
  const int tid = threadIdx.x;
  const int tx = tid & 15, ty = tid >> 4;
  const int row0 = blockIdx.y * 64, col0 = blockIdx.x * 64;
  const int lr = tid >> 2;           // 0..63
  const int lk = (tid & 3) * 4;      // 0,4,8,12
  float acc[4][4] = {};
  for (int k0 = 0; k0 < K; k0 += 16) {
    float4 a4 = *(const float4*)(A + (size_t)(row0 + lr) * K + k0 + lk);
    float4 b4 = *(const float4*)(Bm + (size_t)(col0 + lr) * K + k0 + lk);
    As[lr][lk + 0] = a4.x; As[lr][lk + 1] = a4.y;
    As[lr][lk + 2] = a4.z; As[lr][lk + 3] = a4.w;
    Bs[lr][lk + 0] = b4.x; Bs[lr][lk + 1] = b4.y;
    Bs[lr][lk + 2] = b4.z; Bs[lr][lk + 3] = b4.w;
    __syncthreads();
#pragma unroll
    for (int k = 0; k < 16; ++k) {
      float a0 = As[ty * 4 + 0][k], a1 = As[ty * 4 + 1][k];
      float a2 = As[ty * 4 + 2][k], a3 = As[ty * 4 + 3][k];
      float b0 = Bs[tx * 4 + 0][k], b1 = Bs[tx * 4 + 1][k];
      float b2 = Bs[tx * 4 + 2][k], b3 = Bs[tx * 4 + 3][k];
      acc[0][0] += a0 * b0; acc[0][1] += a0 * b1; acc[0][2] += a0 * b2; acc[0][3] += a0 * b3;
      acc[1][0] += a1 * b0; acc[1][1] += a1 * b1; acc[1][2] += a1 * b2; acc[1][3] += a1 * b3;
      acc[2][0] += a2 * b0; acc[2][1] += a2 * b1; acc[2][2] += a2 * b2; acc[2][3] += a2 * b3;
      acc[3][0] += a3 * b0; acc[3][1] += a3 * b1; acc[3][2] += a3 * b2; acc[3][3] += a3 * b3;
    }
    __syncthreads();
  }
#pragma unroll
  for (int i = 0; i < 4; ++i)
#pragma unroll
    for (int j = 0; j < 4; ++j)
      C[(size_t)(row0 + ty * 4 + i) * N + col0 + tx * 4 + j] = acc[i][j];
}

// ---------------------------------------------------------------------------
// LSTM cell 0: x = [emb(tgt[t,b]) | prev_context], gates over W_ih0 (K=1536)
// + h over W_hh0 (K=1024). Thread = (b, half, dl); grid 256 blocks x 256 thr.
// Each output's K-dim is split across lane pairs (lane, lane+32), combined
// via shfl_xor(32). Writes hB, cB.
// ---------------------------------------------------------------------------
__global__ __launch_bounds__(256) void lstm_cell0_k(
    const float* __restrict__ embedding, const int* __restrict__ tgt,
    const float* __restrict__ ctx,  // prev av [B,D]
    const float* __restrict__ hA, const float* __restrict__ cA,
    float* __restrict__ hB, float* __restrict__ cB,
    const float* __restrict__ W_ih, const float* __restrict__ W_hh,
    const float* __restrict__ b_ih, const float* __restrict__ b_hh, int t) {
  __shared__ float xs[32][132];
  const int tid = threadIdx.x;
  const int b = tid & 31;
  const int half = (tid >> 5) & 1;
  const int dl = tid >> 6;                 // 0..3
  const int d = blockIdx.x * 4 + dl;
  const int bb = tid >> 3;                 // loader: batch row 0..31
  const int kb = (tid & 7) * 16;           // loader: 16 floats each
  const int widx = tgt[t * BB + bb];
  const float* erow = embedding + (size_t)widx * EE;
  const int ks = half * 64;

  float ai = 0.f, af = 0.f, ag = 0.f, ao = 0.f;
  const float* wi = W_ih + (size_t)(0 * DD + d) * 1536;
  const float* wf = W_ih + (size_t)(1 * DD + d) * 1536;
  const float* wg = W_ih + (size_t)(2 * DD + d) * 1536;
  const float* wo = W_ih + (size_t)(3 * DD + d) * 1536;

  // Phase A: embedding columns 0..511
  for (int k0 = 0; k0 < 512; k0 += 128) {
    __syncthreads();
#pragma unroll
    for (int i = 0; i < 16; i += 4)
      *(float4*)&xs[bb][kb + i] = *(const float4*)(erow + k0 + kb + i);
    __syncthreads();
#pragma unroll
    for (int k = 0; k < 64; k += 4) {
      const int col = k0 + ks + k;
      float4 xv = *(const float4*)&xs[b][ks + k];
      float4 vi = *(const float4*)(wi + col);
      float4 vf = *(const float4*)(wf + col);
      float4 vg = *(const float4*)(wg + col);
      float4 vo = *(const float4*)(wo + col);
      ai += xv.x * vi.x + xv.y * vi.y + xv.z * vi.z + xv.w * vi.w;
      af += xv.x * vf.x + xv.y * vf.y + xv.z * vf.z + xv.w * vf.w;
      ag += xv.x * vg.x + xv.y * vg.y + xv.z * vg.z + xv.w * vg.w;
      ao += xv.x * vo.x + xv.y * vo.y + xv.z * vo.z + xv.w * vo.w;
    }
  }
  // Phase B: prev_context, columns 512..1535
  for (int k0 = 0; k0 < 1024; k0 += 128) {
    __syncthreads();
#pragma unroll
    for (int i = 0; i < 16; i += 4)
      *(float4*)&xs[bb][kb + i] = *(const float4*)(ctx + bb * DD + k0 + kb + i);
    __syncthreads();
#pragma unroll
    for (int k = 0; k < 64; k += 4) {
      const int col = 512 + k0 + ks + k;
      float4 xv = *(const float4*)&xs[b][ks + k];
      float4 vi = *(const float4*)(wi + col);
      float4 vf = *(const float4*)(wf + col);
      float4 vg = *(const float4*)(wg + col);
      float4 vo = *(const float4*)(wo + col);
      ai += xv.x * vi.x + xv.y * vi.y + xv.z * vi.z + xv.w * vi.w;
      af += xv.x * vf.x + xv.y * vf.y + xv.z * vf.z + xv.w * vf.w;
      ag += xv.x * vg.x + xv.y * vg.y + xv.z * vg.z + xv.w * vg.w;
      ao += xv.x * vo.x + xv.y * vo.y + xv.z * vo.z + xv.w * vo.w;
    }
  }
  // Phase C: recurrent h with W_hh (K=1024)
  const float* ui = W_hh + (size_t)(0 * DD + d) * 1024;
  const float* uf = W_hh + (size_t)(1 * DD + d) * 1024;
  const float* ug = W_hh + (size_t)(2 * DD + d) * 1024;
  const float* uo = W_hh + (size_t)(3 * DD + d) * 1024;
  for (int k0 = 0; k0 < 1024; k0 += 128) {
    __syncthreads();
#pragma unroll
    for (int i = 0; i < 16; i += 4)
      *(float4*)&xs[bb][kb + i] = *(const float4*)(hA + bb * DD + k0 + kb + i);
    __syncthreads();
#pragma unroll
    for (int k = 0; k < 64; k += 4) {
      const int col = k0 + ks + k;
      float4 xv = *(const float4*)&xs[b][ks + k];
      float4 vi = *(const float4*)(ui + col);
      float4 vf = *(const float4*)(uf + col);
      float4 vg = *(const float4*)(ug + col);
      float4 vo = *(const float4*)(uo + col);
      ai += xv.x * vi.x + xv.y * vi.y + xv.z * vi.z + xv.w * vi.w;
      af += xv.x * vf.x + xv.y * vf.y + xv.z * vf.z + xv.w * vf.w;
      ag += xv.x * vg.x + xv.y * vg.y + xv.z * vg.z + xv.w * vg.w;
      ao += xv.x * vo.x + xv.y * vo.y + xv.z * vo.z + xv.w * vo.w;
    }
  }
  ai += __shfl_xor(ai, 32); af += __shfl_xor(af, 32);
  ag += __shfl_xor(ag, 32); ao += __shfl_xor(ao, 32);
  if (half == 0) {
    ai += b_ih[d] + b_hh[d];
    af += b_ih[DD + d] + b_hh[DD + d];
    ag += b_ih[2 * DD + d] + b_hh[2 * DD + d];
    ao += b_ih[3 * DD + d] + b_hh[3 * DD + d];
    float co = cA[b * DD + d];
    float si = 1.f / (1.f + expf(-ai));
    float sf = 1.f / (1.f + expf(-af));
    float sg = tanhf(ag);
    float so = 1.f / (1.f + expf(-ao));
    float cn = sf * co + si * sg;
    cB[b * DD + d] = cn;
    hB[b * DD + d] = so * tanhf(cn);
  }
}

// ---------------------------------------------------------------------------
// LSTM cell 1: x == h == hB, c = cB. Gates use W_ih1[j,:] + W_hh1[j,:] (same
// K=1024 index space) summed on the fly. Writes hA, cA.
// ---------------------------------------------------------------------------
__global__ __launch_bounds__(256) void lstm_cell1_k(
    const float* __restrict__ hB, const float* __restrict__ cB,
    float* __restrict__ hA, float* __restrict__ cA,
    const float* __restrict__ W_ih, const float* __restrict__ W_hh,
    const float* __restrict__ b_ih, const float* __restrict__ b_hh) {
  __shared__ float xs[32][132];
  const int tid = threadIdx.x;
  const int b = tid & 31;
  const int half = (tid >> 5) & 1;
  const int dl = tid >> 6;
  const int d = blockIdx.x * 4 + dl;
  const int bb = tid >> 3;
  const int kb = (tid & 7) * 16;
  const int ks = half * 64;

  float ai = 0.f, af = 0.f, ag = 0.f, ao = 0.f;
  const float* wi = W_ih + (size_t)(0 * DD + d) * 1024;
  const float* wf = W_ih + (size_t)(1 * DD + d) * 1024;
  const float* wg = W_ih + (size_t)(2 * DD + d) * 1024;
  const float* wo = W_ih + (size_t)(3 * DD + d) * 1024;
  const float* ui = W_hh + (size_t)(0 * DD + d) * 1024;
  const float* uf = W_hh + (size_t)(1 * DD + d) * 1024;
  const float* ug = W_hh + (size_t)(2 * DD + d) * 1024;
  const float* uo = W_hh + (size_t)(3 * DD + d) * 1024;

  for (int k0 = 0; k0 < 1024; k0 += 128) {
    __syncthreads();
#pragma unroll
    for (int i = 0; i < 16; i += 4)
      *(float4*)&xs[bb][kb + i] = *(const float4*)(hB + bb * DD + k0 + kb + i);
    __syncthreads();
#pragma unroll
    for (int k = 0; k < 64; k += 4) {
      const int col = k0 + ks + k;
      float4 xv = *(const float4*)&xs[b][ks + k];
      float4 vi = *(const float4*)(wi + col);
      float4 vf = *(const float4*)(wf + col);
      float4 vg = *(const float4*)(wg + col);
      float4 vo = *(const float4*)(wo + col);
      float4 yi = *(const float4*)(ui + col);
      float4 yf = *(const float4*)(uf + col);
      float4 yg = *(const float4*)(ug + col);
      float4 yo = *(const float4*)(uo + col);
      ai += xv.x * (vi.x + yi.x) + xv.y * (vi.y + yi.y) + xv.z * (vi.z + yi.z) + xv.w * (vi.w + yi.w);
      af += xv.x * (vf.x + yf.x) + xv.y * (vf.y + yf.y) + xv.z * (vf.z + yf.z) + xv.w * (vf.w + yf.w);
      ag += xv.x * (vg.x + yg.x) + xv.y * (vg.y + yg.y) + xv.z * (vg.z + yg.z) + xv.w * (vg.w + yg.w);
      ao += xv.x * (vo.x + yo.x) + xv.y * (vo.y + yo.y) + xv.z * (vo.z + yo.z) + xv.w * (vo.w + yo.w);
    }
  }
  ai += __shfl_xor(ai, 32); af += __shfl_xor(af, 32);
  ag += __shfl_xor(ag, 32); ao += __shfl_xor(ao, 32);
  if (half == 0) {
    ai += b_ih[d] + b_hh[d];
    af += b_ih[DD + d] + b_hh[DD + d];
    ag += b_ih[2 * DD + d] + b_hh[2 * DD + d];
    ao += b_ih[3 * DD + d] + b_hh[3 * DD + d];
    float co = cB[b * DD + d];
    float si = 1.f / (1.f + expf(-ai));
    float sf = 1.f / (1.f + expf(-af));
    float sg = tanhf(ag);
    float so = 1.f / (1.f + expf(-ao));
    float cn = sf * co + si * sg;
    cA[b * DD + d] = cn;
    hA[b * DD + d] = so * tanhf(cn);
  }
}

// ---------------------------------------------------------------------------
// Attention: logits[b,s] = PA[s,b,:]·h[b,:]; softmax over s; context[b,e] =
// sum_s alpha[s] * enc[s,b,e]. One block per batch element.
// ---------------------------------------------------------------------------
__global__ __launch_bounds__(256) void attn_k(
    const float* __restrict__ PA, const float* __restrict__ enc,
    const float* __restrict__ h, float* __restrict__ ctxN) {
  const int b = blockIdx.x;
  __shared__ float hs[DD];
  __shared__ float sm[SS];
  const int tid = threadIdx.x;
  for (int k = tid; k < DD; k += 256) hs[k] = h[b * DD + k];
  __syncthreads();
  const int lane = tid & 63, w = tid >> 6;
  for (int si = 0; si < 16; ++si) {
    const int s = w * 16 + si;
    const float* pa = PA + ((size_t)s * BB + b) * DD;
    float sum = 0.f;
    for (int k = lane; k < DD; k += 64) sum += pa[k] * hs[k];
#pragma unroll
    for (int off = 32; off > 0; off >>= 1) sum += __shfl_xor(sum, off);
    if (lane == 0) sm[s] = sum;
  }
  __syncthreads();
  if (tid < 64) {
    float v = sm[tid];
    float m = v;
#pragma unroll
    for (int off = 32; off > 0; off >>= 1) m = fmaxf(m, __shfl_xor(m, off));
    float e = expf(v - m);
    float s2 = e;
#pragma unroll
    for (int off = 32; off > 0; off >>= 1) s2 += __shfl_xor(s2, off);
    sm[tid] = e / s2;
  }
  __syncthreads();
  for (int e0 = tid; e0 < TE; e0 += 256) {
    float acc = 0.f;
#pragma unroll 8
    for (int s = 0; s < SS; ++s) acc += sm[s] * enc[((size_t)s * BB + b) * TE + e0];
    ctxN[b * TE + e0] = acc;
  }
}

// ---------------------------------------------------------------------------
// Combine: av[b,d] = tanh( [h | context] · W_combine[d,:] ), K=2048.
// Writes av (next prev_context) and av_all[t].
// ---------------------------------------------------------------------------
__global__ __launch_bounds__(256) void combine_k(
    const float* __restrict__ hA, const float* __restrict__ ctxN,
    const float* __restrict__ Wc, float* __restrict__ av,
    float* __restrict__ av_all_t) {
  __shared__ float xs[32][132];
  const int tid = threadIdx.x;
  const int b = tid & 31;
  const int half = (tid >> 5) & 1;
  const int dl = tid >> 6;
  const int d = blockIdx.x * 4 + dl;
  const int bb = tid >> 3;
  const int kb = (tid & 7) * 16;
  const int ks = half * 64;
  float acc = 0.f;
  const float* w0 = Wc + (size_t)d * 2048;
  for (int k0 = 0; k0 < 1024; k0 += 128) {
    __syncthreads();
#pragma unroll
    for (int i = 0; i < 16; i += 4)
      *(float4*)&xs[bb][kb + i] = *(const float4*)(hA + bb * DD + k0 + kb + i);
    __syncthreads();
#pragma unroll
    for (int k = 0; k < 64; k += 4) {
      const int col = k0 + ks + k;
      float4 xv = *(const float4*)&xs[b][ks + k];
      float4 wv = *(const float4*)(w0 + col);
      acc += xv.x * wv.x + xv.y * wv.y + xv.z * wv.z + xv.w * wv.w;
    }
  }
  for (int k0 = 0; k0 < 1024; k0 += 128) {
    __syncthreads();
#pragma unroll
    for (int i = 0; i < 16; i += 4)
      *(float4*)&xs[bb][kb + i] = *(const float4*)(ctxN + bb * TE + k0 + kb + i);
    __syncthreads();
#pragma unroll
    for (int k = 0; k < 64; k += 4) {
      const int col = 1024 + k0 + ks + k;
      float4 xv = *(const float4*)&xs[b][ks + k];
      float4 wv = *(const float4*)(w0 + col);
      acc += xv.x * wv.x + xv.y * wv.y + xv.z * wv.z + xv.w * wv.w;
    }
  }
  acc += __shfl_xor(acc, 32);
  if (half == 0) {
    float v = tanhf(acc);
    av[b * DD + d] = v;
    av_all_t[b * DD + d] = v;
  }
}

// ---------------------------------------------------------------------------
extern "C" void kernel_launch(void* const* d_in, const int* in_sizes, int n_in,
                              void* d_out, int out_size, void* d_ws, size_t ws_size,
                              hipStream_t stream) {
  const float* enc   = (const float*)d_in[0];
  const float* h0    = (const float*)d_in[1];
  const float* c0    = (const float*)d_in[2];
  const float* emb   = (const float*)d_in[3];
  const float* Wproj = (const float*)d_in[4];
  const float* Wcomb = (const float*)d_in[5];
  const float* Wout  = (const float*)d_in[6];
  const float* Wih0  = (const float*)d_in[7];
  const float* Whh0  = (const float*)d_in[8];
  const float* bih0  = (const float*)d_in[9];
  const float* bhh0  = (const float*)d_in[10];
  const float* Wih1  = (const float*)d_in[11];
  const float* Whh1  = (const float*)d_in[12];
  const float* bih1  = (const float*)d_in[13];
  const float* bhh1  = (const float*)d_in[14];
  const int*   tgt   = (const int*)d_in[15];
  float* out = (float*)d_out;

  float* ws = (float*)d_ws;
  float* PA = ws;      ws += (size_t)SS * BB * DD;   // [S,B,D] attn_scores
  float* hA = ws;      ws += BB * DD;
  float* cA = ws;      ws += BB * DD;
  float* hB = ws;      ws += BB * DD;
  float* cB = ws;      ws += BB * DD;
  float* av = ws;      ws += BB * DD;                // prev_context
  float* ctxN = ws;    ws += BB * TE;                // attention context
  float* av_all = ws;  ws += (size_t)TT * BB * DD;   // [T,B,D]

  init_k<<<128, 256, 0, stream>>>(h0, c0, hA, cA, av);
  // PA[(s*B+b), d] = enc[(s*B+b), :] . Wproj[d, :]
  gemm_nt<<<dim3(DD / 64, (SS * BB) / 64), 256, 0, stream>>>(enc, Wproj, PA,
                                                             SS * BB, DD, TE);
  for (int t = 0; t < TT; ++t) {
    lstm_cell0_k<<<256, 256, 0, stream>>>(emb, tgt, av, hA, cA, hB, cB,
                                          Wih0, Whh0, bih0, bhh0, t);
    lstm_cell1_k<<<256, 256, 0, stream>>>(hB, cB, hA, cA, Wih1, Whh1, bih1, bhh1);
    attn_k<<<32, 256, 0, stream>>>(PA, enc, hA, ctxN);
    combine_k<<<256, 256, 0, stream>>>(hA, ctxN, Wcomb, av,
                                       av_all + (size_t)t * BB * DD);
  }
  // scores[(t*B+b), v] = av_all[(t*B+b), :] . Wout[v, :]
  gemm_nt<<<dim3(VV / 64, (TT * BB) / 64), 256, 0, stream>>>(av_all, Wout, out,
                                                             TT * BB, VV, DD);
}

// Round 2
// 7933.278 us; speedup vs baseline: 1.7647x; 1.7647x over previous
//
#include <hip/hip_runtime.h>
#include <hip/hip_bf16.h>
#include <math.h>

#define VV 32000
#define EE 512
#define DD 1024
#define TE 1024
#define BB 32
#define SS 64
#define TT 48

typedef __attribute__((ext_vector_type(8))) short short8;
typedef __attribute__((ext_vector_type(4))) float f32x4;

__device__ __forceinline__ unsigned short f2b(float x) {
  unsigned int u = __float_as_uint(x);
  u += 0x7fff + ((u >> 16) & 1);
  return (unsigned short)(u >> 16);
}

#define GLDS16(g, l)                                                      \
  __builtin_amdgcn_global_load_lds(                                       \
      (const __attribute__((address_space(1))) void*)(g),                 \
      (__attribute__((address_space(3))) void*)(l), 16, 0, 0)

// ---------------------------------------------------------------------------
// fp32 -> bf16 elementwise, 4-wide, grid-stride
// ---------------------------------------------------------------------------
__global__ void f2b4_k(const float4* __restrict__ src,
                       ushort4* __restrict__ dst, int n4) {
  for (int i = blockIdx.x * 256 + threadIdx.x; i < n4; i += gridDim.x * 256) {
    float4 v = src[i];
    ushort4 o;
    o.x = f2b(v.x); o.y = f2b(v.y); o.z = f2b(v.z); o.w = f2b(v.w);
    dst[i] = o;
  }
}

// ---------------------------------------------------------------------------
// Build W0b[row=d*4+g][k] = bf16( k<1536 ? Wih0[g*1024+d][k] : Whh0[g*1024+d][k-1536] )
// bsum0[row] = bih0[g*1024+d] + bhh0[g*1024+d]
// ---------------------------------------------------------------------------
__global__ void build_w0_k(const float* __restrict__ Wih, const float* __restrict__ Whh,
                           unsigned short* __restrict__ W0b,
                           const float* __restrict__ bih, const float* __restrict__ bhh,
                           float* __restrict__ bsum) {
  const int row = blockIdx.x;            // 0..4095 = d*4+g
  const int d = row >> 2, g = row & 3;
  const int src = g * 1024 + d;
  const float* a = Wih + (size_t)src * 1536;
  const float* b = Whh + (size_t)src * 1024;
  unsigned short* o = W0b + (size_t)row * 2560;
  for (int k = threadIdx.x; k < 1536; k += 256) o[k] = f2b(a[k]);
  for (int k = threadIdx.x; k < 1024; k += 256) o[1536 + k] = f2b(b[k]);
  if (threadIdx.x == 0) bsum[row] = bih[src] + bhh[src];
}

// ---------------------------------------------------------------------------
// Build W1b[row=d*4+g][k] = bf16(Wih1[g*1024+d][k] + Whh1[g*1024+d][k])  (x==h fold)
// ---------------------------------------------------------------------------
__global__ void build_w1_k(const float* __restrict__ Wih, const float* __restrict__ Whh,
                           unsigned short* __restrict__ W1b,
                           const float* __restrict__ bih, const float* __restrict__ bhh,
                           float* __restrict__ bsum) {
  const int row = blockIdx.x;
  const int d = row >> 2, g = row & 3;
  const int src = g * 1024 + d;
  const float* a = Wih + (size_t)src * 1024;
  const float* b = Whh + (size_t)src * 1024;
  unsigned short* o = W1b + (size_t)row * 1024;
  for (int k = threadIdx.x; k < 1024; k += 256) o[k] = f2b(a[k] + b[k]);
  if (threadIdx.x == 0) bsum[row] = bih[src] + bhh[src];
}

// ---------------------------------------------------------------------------
// Gather embeddings for every (t,b) into X0buf[t][b][0:512] (bf16)
// ---------------------------------------------------------------------------
__global__ void emb_k(const float* __restrict__ emb, const int* __restrict__ tgt,
                      unsigned short* __restrict__ X0buf) {
  const int tb = blockIdx.x;   // 0..T*B-1
  const float* src = emb + (size_t)tgt[tb] * EE;
  unsigned short* dst = X0buf + (size_t)tb * 2560;
  const int i = threadIdx.x * 4;
  float4 v = *(const float4*)(src + i);
  dst[i] = f2b(v.x); dst[i + 1] = f2b(v.y); dst[i + 2] = f2b(v.z); dst[i + 3] = f2b(v.w);
}

// ---------------------------------------------------------------------------
// init: X0buf[0] av-part = 0, h-part = bf16(h0); cA = c0
// ---------------------------------------------------------------------------
__global__ void init2_k(const float* __restrict__ h0, const float* __restrict__ c0,
                        unsigned short* __restrict__ X0buf, float* __restrict__ cA) {
  const int i = blockIdx.x * 256 + threadIdx.x;
  if (i < BB * DD) {
    const int b = i >> 10, d = i & 1023;
    unsigned short* r = X0buf + (size_t)b * 2560;
    r[512 + d] = 0;
    r[1536 + d] = f2b(h0[i]);
    cA[i] = c0[i];
  }
}

// ---------------------------------------------------------------------------
// Big MFMA GEMM: C[M,N] fp32 = A[M,K] bf16 @ B[N,K]^T bf16.  128x128 tile,
// 256 threads / 4 waves, each wave 64x64 (4x4 of 16x16x32 MFMA), BK=32.
// ---------------------------------------------------------------------------
__global__ __launch_bounds__(256) void gemm_big(
    const unsigned short* __restrict__ A, const unsigned short* __restrict__ B,
    float* __restrict__ C, int M, int N, int K) {
  __shared__ unsigned short As[128 * 32];
  __shared__ unsigned short Bs[128 * 32];
  const int tid = threadIdx.x;
  const int wid = tid >> 6, lane = tid & 63;
  const int row0 = blockIdx.y * 128, col0 = blockIdx.x * 128;
  const int wm = (wid >> 1) * 64, wn = (wid & 1) * 64;
  f32x4 acc[4][4] = {};
  const int lr = tid >> 2;           // staging row 0..63
  const int lc = (tid & 3) * 8;      // staging k-offset (bf16)
  const unsigned short* Ag = A + (size_t)(row0 + lr) * K + lc;
  const unsigned short* Bg = B + (size_t)(col0 + lr) * K + lc;
  unsigned short* Al = As + lr * 32 + lc;
  unsigned short* Bl = Bs + lr * 32 + lc;
  const int fr = lane & 15, fq = (lane >> 4) * 8;
  for (int k0 = 0; k0 < K; k0 += 32) {
    GLDS16(Ag + k0, Al);
    GLDS16(Ag + (size_t)64 * K + k0, Al + 64 * 32);
    GLDS16(Bg + k0, Bl);
    GLDS16(Bg + (size_t)64 * K + k0, Bl + 64 * 32);
    __syncthreads();
    short8 af[4], bfr[4];
#pragma unroll
    for (int i = 0; i < 4; ++i) {
      af[i]  = *(const short8*)(As + (wm + i * 16 + fr) * 32 + fq);
      bfr[i] = *(const short8*)(Bs + (wn + i * 16 + fr) * 32 + fq);
    }
#pragma unroll
    for (int i = 0; i < 4; ++i)
#pragma unroll
      for (int j = 0; j < 4; ++j)
        acc[i][j] = __builtin_amdgcn_mfma_f32_16x16x32_bf16(af[i], bfr[j], acc[i][j], 0, 0, 0);
    __syncthreads();
  }
  const int cn = lane & 15, cr = (lane >> 4) * 4;
#pragma unroll
  for (int i = 0; i < 4; ++i)
#pragma unroll
    for (int j = 0; j < 4; ++j)
#pragma unroll
      for (int r = 0; r < 4; ++r)
        C[(size_t)(row0 + wm + i * 16 + cr + r) * N + col0 + wn + j * 16 + cn] = acc[i][j][r];
}

// ---------------------------------------------------------------------------
// Small step GEMM core: acc[2] (32m x 16n per wave) = X[32,K] @ W[N,K]^T over
// block cols [col0, col0+64). 256 threads / 4 waves; wave w owns n-tile w.
// ---------------------------------------------------------------------------
__device__ __forceinline__ void small_gemm(
    const unsigned short* __restrict__ X, const unsigned short* __restrict__ W,
    int K, int col0, unsigned short* As, unsigned short* Bs, f32x4 acc[2]) {
  const int tid = threadIdx.x;
  const int wid = tid >> 6, lane = tid & 63;
  const unsigned short* Bg = W + (size_t)(col0 + (tid >> 2)) * K + (tid & 3) * 8;
  const unsigned short* Ag = X + (size_t)(tid >> 2) * K + (tid & 3) * 8;  // tid<128
  const int fr = lane & 15, fq = (lane >> 4) * 8;
  for (int k0 = 0; k0 < K; k0 += 32) {
    if (tid < 128) GLDS16(Ag + k0, As + tid * 8);
    GLDS16(Bg + k0, Bs + tid * 8);
    __syncthreads();
    short8 a0 = *(const short8*)(As + fr * 32 + fq);
    short8 a1 = *(const short8*)(As + (16 + fr) * 32 + fq);
    short8 b0 = *(const short8*)(Bs + (wid * 16 + fr) * 32 + fq);
    acc[0] = __builtin_amdgcn_mfma_f32_16x16x32_bf16(a0, b0, acc[0], 0, 0, 0);
    acc[1] = __builtin_amdgcn_mfma_f32_16x16x32_bf16(a1, b0, acc[1], 0, 0, 0);
    __syncthreads();
  }
}

__device__ __forceinline__ float sigm(float x) { return 1.f / (1.f + __expf(-x)); }

// ---------------------------------------------------------------------------
// Cell0: gates = X0 @ W0b^T (K=2560, gate-interleaved cols), LSTM update.
// Writes cB (fp32) and h -> X1 (bf16). Grid 64 blocks (4096 cols / 64).
// ---------------------------------------------------------------------------
__global__ __launch_bounds__(256) void cell0_k(
    const unsigned short* __restrict__ X0, const unsigned short* __restrict__ W0b,
    const float* __restrict__ bsum, const float* __restrict__ cA,
    float* __restrict__ cB, unsigned short* __restrict__ X1) {
  __shared__ unsigned short As[32 * 32], Bs[64 * 32];
  __shared__ float Gs[32][64];
  const int tid = threadIdx.x, wid = tid >> 6, lane = tid & 63;
  const int col0 = blockIdx.x * 64;
  f32x4 acc[2] = {};
  small_gemm(X0, W0b, 2560, col0, As, Bs, acc);
  const int cn = wid * 16 + (lane & 15);
  const float bv = bsum[col0 + cn];
  const int cr = (lane >> 4) * 4;
#pragma unroll
  for (int r = 0; r < 4; ++r) {
    Gs[cr + r][cn] = acc[0][r] + bv;
    Gs[16 + cr + r][cn] = acc[1][r] + bv;
  }
  __syncthreads();
  for (int idx = tid; idx < 512; idx += 256) {
    const int b = idx >> 4, dl = idx & 15;
    const int d = (col0 >> 2) + dl;
    const float gi = Gs[b][dl * 4 + 0], gf = Gs[b][dl * 4 + 1];
    const float gg = Gs[b][dl * 4 + 2], go = Gs[b][dl * 4 + 3];
    const float cold = cA[b * DD + d];
    const float cnew = sigm(gf) * cold + sigm(gi) * tanhf(gg);
    cB[b * DD + d] = cnew;
    X1[b * DD + d] = f2b(sigm(go) * tanhf(cnew));
  }
}

// ---------------------------------------------------------------------------
// Cell1: gates = X1 @ W1b^T (K=1024). Writes cA, hA (fp32), h bf16 -> Xc[:,0:1024)
// and X0next[:,1536:2560).
// ---------------------------------------------------------------------------
__global__ __launch_bounds__(256) void cell1_k(
    const unsigned short* __restrict__ X1, const unsigned short* __restrict__ W1b,
    const float* __restrict__ bsum, const float* __restrict__ cB,
    float* __restrict__ cA, float* __restrict__ hA,
    unsigned short* __restrict__ Xc, unsigned short* __restrict__ X0n) {
  __shared__ unsigned short As[32 * 32], Bs[64 * 32];
  __shared__ float Gs[32][64];
  const int tid = threadIdx.x, wid = tid >> 6, lane = tid & 63;
  const int col0 = blockIdx.x * 64;
  f32x4 acc[2] = {};
  small_gemm(X1, W1b, 1024, col0, As, Bs, acc);
  const int cn = wid * 16 + (lane & 15);
  const float bv = bsum[col0 + cn];
  const int cr = (lane >> 4) * 4;
#pragma unroll
  for (int r = 0; r < 4; ++r) {
    Gs[cr + r][cn] = acc[0][r] + bv;
    Gs[16 + cr + r][cn] = acc[1][r] + bv;
  }
  __syncthreads();
  for (int idx = tid; idx < 512; idx += 256) {
    const int b = idx >> 4, dl = idx & 15;
    const int d = (col0 >> 2) + dl;
    const float gi = Gs[b][dl * 4 + 0], gf = Gs[b][dl * 4 + 1];
    const float gg = Gs[b][dl * 4 + 2], go = Gs[b][dl * 4 + 3];
    const float cold = cB[b * DD + d];
    const float cnew = sigm(gf) * cold + sigm(gi) * tanhf(gg);
    cA[b * DD + d] = cnew;
    const float h = sigm(go) * tanhf(cnew);
    hA[b * DD + d] = h;
    const unsigned short hb = f2b(h);
    Xc[b * 2048 + d] = hb;
    X0n[(size_t)b * 2560 + 1536 + d] = hb;
  }
}

// ---------------------------------------------------------------------------
// Attention (fp32): logits from PA·h, softmax, context = alpha·enc -> bf16 Xc[:,1024:)
// ---------------------------------------------------------------------------
__global__ __launch_bounds__(256) void attn_k(
    const float* __restrict__ PA, const float* __restrict__ enc,
    const float* __restrict__ h, unsigned short* __restrict__ Xc) {
  const int b = blockIdx.x;
  __shared__ float hs[DD];
  __shared__ float sm[SS];
  const int tid = threadIdx.x;
  for (int k = tid; k < DD; k += 256) hs[k] = h[b * DD + k];
  __syncthreads();
  const int lane = tid & 63, w = tid >> 6;
  for (int si = 0; si < 16; ++si) {
    const int s = w * 16 + si;
    const float* pa = PA + ((size_t)s * BB + b) * DD;
    float sum = 0.f;
    for (int k = lane; k < DD; k += 64) sum += pa[k] * hs[k];
#pragma unroll
    for (int off = 32; off > 0; off >>= 1) sum += __shfl_xor(sum, off);
    if (lane == 0) sm[s] = sum;
  }
  __syncthreads();
  if (tid < 64) {
    float v = sm[tid];
    float m = v;
#pragma unroll
    for (int off = 32; off > 0; off >>= 1) m = fmaxf(m, __shfl_xor(m, off));
    float e = __expf(v - m);
    float s2 = e;
#pragma unroll
    for (int off = 32; off > 0; off >>= 1) s2 += __shfl_xor(s2, off);
    sm[tid] = e / s2;
  }
  __syncthreads();
  for (int e0 = tid; e0 < TE; e0 += 256) {
    float acc = 0.f;
#pragma unroll 8
    for (int s = 0; s < SS; ++s) acc += sm[s] * enc[((size_t)s * BB + b) * TE + e0];
    Xc[b * 2048 + 1024 + e0] = f2b(acc);
  }
}

// ---------------------------------------------------------------------------
// Combine: av = tanh(Xc[32,2048] @ Wcb[1024,2048]^T). Writes av bf16 to
// X0next[:,512:1536) and av_all_t. Grid 16 blocks.
// ---------------------------------------------------------------------------
__global__ __launch_bounds__(256) void combine_k(
    const unsigned short* __restrict__ Xc, const unsigned short* __restrict__ Wcb,
    unsigned short* __restrict__ X0n, unsigned short* __restrict__ av_all_t) {
  __shared__ unsigned short As[32 * 32], Bs[64 * 32];
  const int tid = threadIdx.x, wid = tid >> 6, lane = tid & 63;
  const int col0 = blockIdx.x * 64;
  f32x4 acc[2] = {};
  small_gemm(Xc, Wcb, 2048, col0, As, Bs, acc);
  const int n = col0 + wid * 16 + (lane & 15);
  const int cr = (lane >> 4) * 4;
#pragma unroll
  for (int mt = 0; mt < 2; ++mt)
#pragma unroll
    for (int r = 0; r < 4; ++r) {
      const int b = mt * 16 + cr + r;
      const unsigned short vb = f2b(tanhf(acc[mt][r]));
      X0n[(size_t)b * 2560 + 512 + n] = vb;
      av_all_t[(size_t)b * DD + n] = vb;
    }
}

// ---------------------------------------------------------------------------
extern "C" void kernel_launch(void* const* d_in, const int* in_sizes, int n_in,
                              void* d_out, int out_size, void* d_ws, size_t ws_size,
                              hipStream_t stream) {
  const float* enc   = (const float*)d_in[0];
  const float* h0    = (const float*)d_in[1];
  const float* c0    = (const float*)d_in[2];
  const float* emb   = (const float*)d_in[3];
  const float* Wproj = (const float*)d_in[4];
  const float* Wcomb = (const float*)d_in[5];
  const float* Wout  = (const float*)d_in[6];
  const float* Wih0  = (const float*)d_in[7];
  const float* Whh0  = (const float*)d_in[8];
  const float* bih0  = (const float*)d_in[9];
  const float* bhh0  = (const float*)d_in[10];
  const float* Wih1  = (const float*)d_in[11];
  const float* Whh1  = (const float*)d_in[12];
  const float* bih1  = (const float*)d_in[13];
  const float* bhh1  = (const float*)d_in[14];
  const int*   tgt   = (const int*)d_in[15];
  float* out = (float*)d_out;

  char* p = (char*)d_ws;
  auto alloc = [&](size_t bytes) { char* r = p; p += (bytes + 255) & ~(size_t)255; return r; };
  unsigned short* X0buf   = (unsigned short*)alloc((size_t)(TT + 1) * BB * 2560 * 2);
  unsigned short* X1      = (unsigned short*)alloc((size_t)BB * DD * 2);
  unsigned short* Xc      = (unsigned short*)alloc((size_t)BB * 2048 * 2);
  unsigned short* enc_bf  = (unsigned short*)alloc((size_t)SS * BB * TE * 2);
  unsigned short* Wproj_bf= (unsigned short*)alloc((size_t)DD * TE * 2);
  unsigned short* Wcb     = (unsigned short*)alloc((size_t)DD * 2048 * 2);
  unsigned short* Wout_bf = (unsigned short*)alloc((size_t)VV * DD * 2);
  unsigned short* W0b     = (unsigned short*)alloc((size_t)4096 * 2560 * 2);
  unsigned short* W1b     = (unsigned short*)alloc((size_t)4096 * 1024 * 2);
  unsigned short* av_all  = (unsigned short*)alloc((size_t)TT * BB * DD * 2);
  float* PA    = (float*)alloc((size_t)SS * BB * DD * 4);
  float* cA    = (float*)alloc((size_t)BB * DD * 4);
  float* cB    = (float*)alloc((size_t)BB * DD * 4);
  float* hA    = (float*)alloc((size_t)BB * DD * 4);
  float* bsum0 = (float*)alloc(4096 * 4);
  float* bsum1 = (float*)alloc(4096 * 4);

  // --- one-time prep ---
  f2b4_k<<<2048, 256, 0, stream>>>((const float4*)enc, (ushort4*)enc_bf, SS * BB * TE / 4);
  f2b4_k<<<1024, 256, 0, stream>>>((const float4*)Wproj, (ushort4*)Wproj_bf, DD * TE / 4);
  f2b4_k<<<2048, 256, 0, stream>>>((const float4*)Wcomb, (ushort4*)Wcb, DD * 2048 / 4);
  f2b4_k<<<4096, 256, 0, stream>>>((const float4*)Wout, (ushort4*)Wout_bf, VV * DD / 4);
  build_w0_k<<<4096, 256, 0, stream>>>(Wih0, Whh0, W0b, bih0, bhh0, bsum0);
  build_w1_k<<<4096, 256, 0, stream>>>(Wih1, Whh1, W1b, bih1, bhh1, bsum1);
  emb_k<<<TT * BB, 128, 0, stream>>>(emb, tgt, X0buf);
  init2_k<<<128, 256, 0, stream>>>(h0, c0, X0buf, cA);
  // PA = enc @ Wproj^T  (M=2048, N=1024, K=1024)
  gemm_big<<<dim3(TE / 128, (SS * BB) / 128), 256, 0, stream>>>(
      enc_bf, Wproj_bf, PA, SS * BB, DD, TE);

  // --- decode loop ---
  for (int t = 0; t < TT; ++t) {
    const unsigned short* X0 = X0buf + (size_t)t * BB * 2560;
    unsigned short* X0n = X0buf + (size_t)(t + 1) * BB * 2560;
    cell0_k<<<64, 256, 0, stream>>>(X0, W0b, bsum0, cA, cB, X1);
    cell1_k<<<64, 256, 0, stream>>>(X1, W1b, bsum1, cB, cA, hA, Xc, X0n);
    attn_k<<<BB, 256, 0, stream>>>(PA, enc, hA, Xc);
    combine_k<<<16, 256, 0, stream>>>(Xc, Wcb, X0n, av_all + (size_t)t * BB * DD);
  }
  // scores = av_all @ Wout^T  (M=1536, N=32000, K=1024)
  gemm_big<<<dim3(VV / 128, (TT * BB) / 128), 256, 0, stream>>>(
      av_all, Wout_bf, out, TT * BB, VV, DD);
}